// Round 11
// baseline (316.951 us; speedup 1.0000x reference)
//
#include <hip/hip_runtime.h>

// Problem constants (match reference)
#define U_NODES 100000
#define I_NODES 50000
#define N_NODES 150000   // U + I
#define EMB_D   64
#define FEAT_K  256
#define N_LAYERS 4

typedef __attribute__((ext_vector_type(8))) short short8;
typedef __attribute__((ext_vector_type(4))) float f32x4;

// f32 -> bf16 round-to-nearest-even (bit trick)
static __device__ __forceinline__ unsigned short f2bf(float f) {
    unsigned u = __builtin_bit_cast(unsigned, f);
    u += 0x7fffu + ((u >> 16) & 1u);
    return (unsigned short)(u >> 16);
}
static __device__ __forceinline__ float bflo(unsigned u) {
    return __builtin_bit_cast(float, u << 16);
}
static __device__ __forceinline__ float bfhi(unsigned u) {
    return __builtin_bit_cast(float, u & 0xffff0000u);
}

// ---------------------------------------------------------------------------
__global__ __launch_bounds__(256) void k_count(const int* __restrict__ col,
                                               int* __restrict__ deg, int E) {
    int e = blockIdx.x * 256 + threadIdx.x;
    if (e < E) atomicAdd(&deg[col[e]], 1);
}

__global__ __launch_bounds__(256) void k_dinv(const int* __restrict__ deg,
                                              float* __restrict__ dinv, int n) {
    int i = blockIdx.x * 256 + threadIdx.x;
    if (i < n) {
        int d = deg[i];
        dinv[i] = (d > 0) ? rsqrtf((float)d) : 0.0f;
    }
}

__global__ __launch_bounds__(256) void k_scan_a(const int* __restrict__ deg,
                                                int* __restrict__ rs,
                                                int* __restrict__ bsum, int n) {
    __shared__ int wsum[4];
    int t = threadIdx.x;
    int i = blockIdx.x * 256 + t;
    int v = (i < n) ? deg[i] : 0;
    int x = v;
    #pragma unroll
    for (int off = 1; off < 64; off <<= 1) {
        int y = __shfl_up(x, off, 64);
        if ((t & 63) >= off) x += y;
    }
    if ((t & 63) == 63) wsum[t >> 6] = x;
    __syncthreads();
    int base = 0;
    #pragma unroll
    for (int w = 0; w < 4; ++w) base += (w < (t >> 6)) ? wsum[w] : 0;
    if (i < n) rs[i] = base + x - v;
    if (t == 255) bsum[blockIdx.x] = base + x;
}

__global__ __launch_bounds__(1024) void k_scan_b(int* __restrict__ bs, int nb) {
    __shared__ int wsum[16];
    int t = threadIdx.x;
    int v = (t < nb) ? bs[t] : 0;
    int x = v;
    #pragma unroll
    for (int off = 1; off < 64; off <<= 1) {
        int y = __shfl_up(x, off, 64);
        if ((t & 63) >= off) x += y;
    }
    if ((t & 63) == 63) wsum[t >> 6] = x;
    __syncthreads();
    int base = 0;
    #pragma unroll
    for (int w = 0; w < 16; ++w) base += (w < (t >> 6)) ? wsum[w] : 0;
    if (t < nb) bs[t] = base + x - v;
}

__global__ __launch_bounds__(256) void k_scan_c(int* __restrict__ rs,
                                                const int* __restrict__ bsum,
                                                int* __restrict__ cursor,
                                                int n, int E) {
    int i = blockIdx.x * 256 + threadIdx.x;
    if (i < n) {
        int v = rs[i] + bsum[blockIdx.x];
        rs[i] = v;
        cursor[i] = v;
    }
    if (i == 0) rs[n] = E;
}

// CSR fill: ONE scattered 4B nontemporal write per edge (src index only;
// norm is recomputed in the agg kernels from the L2-hot dinv table).
// R10 A/B: 8B payload -> WRITE_SIZE 67 MB (line-granular writeback). 4B
// payload should halve it; if dur doesn't move, the cursor atomics dominate.
__global__ __launch_bounds__(256) void k_fill(const int* __restrict__ row,
                                              const int* __restrict__ col,
                                              int* __restrict__ cursor,
                                              int* __restrict__ csr_src, int E) {
    int e = blockIdx.x * 256 + threadIdx.x;
    if (e < E) {
        int r = row[e], c = col[e];
        int p = atomicAdd(&cursor[c], 1);
        __builtin_nontemporal_store(r, &csr_src[p]);
    }
}

// Convert W matrices to bf16 (once per call; 32K elements total)
__global__ __launch_bounds__(256) void k_cvtw(const float* __restrict__ wu,
                                              const float* __restrict__ wi,
                                              unsigned short* __restrict__ wub,
                                              unsigned short* __restrict__ wib) {
    int i = blockIdx.x * 256 + threadIdx.x;
    if (i < EMB_D * FEAT_K) wub[i] = f2bf(wu[i]);
    else                    wib[i - EMB_D * FEAT_K] = f2bf(wi[i - EMB_D * FEAT_K]);
}

// Init: x0 (bf16) = concat(emb_users, emb_items). One thread per 8 elements.
__global__ __launch_bounds__(256) void k_init(const float4* __restrict__ eu,
                                              const float4* __restrict__ ei,
                                              uint4* __restrict__ x,
                                              int n8u, int n8) {
    int i = blockIdx.x * 256 + threadIdx.x;
    if (i >= n8) return;
    const float4* s = (i < n8u) ? (eu + (size_t)i * 2) : (ei + (size_t)(i - n8u) * 2);
    float4 p0 = s[0], p1 = s[1];
    uint4 r;
    r.x = (unsigned)f2bf(p0.x) | ((unsigned)f2bf(p0.y) << 16);
    r.y = (unsigned)f2bf(p0.z) | ((unsigned)f2bf(p0.w) << 16);
    r.z = (unsigned)f2bf(p1.x) | ((unsigned)f2bf(p1.y) << 16);
    r.w = (unsigned)f2bf(p1.z) | ((unsigned)f2bf(p1.w) << 16);
    x[i] = r;
}

// NOTE: macro params use trailing-underscore names (R5 lesson: never collide
// with .x/.y/.z/.w member tokens).
#define ACC8(v_, w_)                       \
    s0 = fmaf(bflo((v_).x), (w_), s0);     \
    s1 = fmaf(bfhi((v_).x), (w_), s1);     \
    s2 = fmaf(bflo((v_).y), (w_), s2);     \
    s3 = fmaf(bfhi((v_).y), (w_), s3);     \
    s4 = fmaf(bflo((v_).z), (w_), s4);     \
    s5 = fmaf(bfhi((v_).z), (w_), s5);     \
    s6 = fmaf(bflo((v_).w), (w_), s6);     \
    s7 = fmaf(bfhi((v_).w), (w_), s7);

// Masked 4-wide gather round: always 4 outstanding row-gathers; OOB lanes
// clamped to the last edge with weight zeroed. Weight = dinv[src]*dinv[node],
// with dinv[src] gathered from the 600 KB L2-hot table (rides in parallel
// with the 128B x-row gather).
#define GATHER4(xsrc_, ep_, em_, dn_)                                         \
    {                                                                         \
        int i0_ = (ep_), i1_ = min((ep_) + 1, (em_));                         \
        int i2_ = min((ep_) + 2, (em_)), i3_ = min((ep_) + 3, (em_));         \
        int sa_ = csr_src[i0_], sb_ = csr_src[i1_];                           \
        int sc_ = csr_src[i2_], sd_ = csr_src[i3_];                           \
        float wa_ = dinv[sa_] * (dn_);                                        \
        float wb_ = ((ep_) + 1 <= (em_)) ? dinv[sb_] * (dn_) : 0.f;           \
        float wc_ = ((ep_) + 2 <= (em_)) ? dinv[sc_] * (dn_) : 0.f;           \
        float wd_ = ((ep_) + 3 <= (em_)) ? dinv[sd_] * (dn_) : 0.f;           \
        uint4 va_ = (xsrc_)[(size_t)sa_ * 8 + lane];                          \
        uint4 vb_ = (xsrc_)[(size_t)sb_ * 8 + lane];                          \
        uint4 vc_ = (xsrc_)[(size_t)sc_ * 8 + lane];                          \
        uint4 vd_ = (xsrc_)[(size_t)sd_ * 8 + lane];                          \
        ACC8(va_, wa_) ACC8(vb_, wb_) ACC8(vc_, wc_) ACC8(vd_, wd_)           \
    }

// Pull-mode aggregation (layers 1..3), bf16 state: 8 lanes/node, 16B/lane.
__global__ __launch_bounds__(256) void k_agg(const uint4* __restrict__ xin,
                                             uint4* __restrict__ xout,
                                             const int* __restrict__ rs,
                                             const int* __restrict__ csr_src,
                                             const float* __restrict__ dinv,
                                             int n_nodes) {
    int idx = blockIdx.x * 256 + threadIdx.x;
    int node = idx >> 3;
    int lane = idx & 7;
    if (node >= n_nodes) return;
    int e0 = rs[node], e1 = rs[node + 1];
    float dn = dinv[node];
    float s0 = 0.f, s1 = 0.f, s2 = 0.f, s3 = 0.f;
    float s4 = 0.f, s5 = 0.f, s6 = 0.f, s7 = 0.f;
    int em = e1 - 1;
    for (int ep = e0; ep < e1; ep += 4) GATHER4(xin, ep, em, dn)
    uint4 r;
    r.x = (unsigned)f2bf(s0) | ((unsigned)f2bf(s1) << 16);
    r.y = (unsigned)f2bf(s2) | ((unsigned)f2bf(s3) << 16);
    r.z = (unsigned)f2bf(s4) | ((unsigned)f2bf(s5) << 16);
    r.w = (unsigned)f2bf(s6) | ((unsigned)f2bf(s7) << 16);
    xout[(size_t)node * 8 + lane] = r;
}

// Layer 4 + fused sum: s = gather(x3); out_row = (emb + x1 + x2 + x3 + s)/25
__global__ __launch_bounds__(256) void k_agg4(const uint4* __restrict__ x3,
                                              const uint4* __restrict__ x1,
                                              const uint4* __restrict__ x2,
                                              const float* __restrict__ embU,
                                              const float* __restrict__ embI,
                                              float* __restrict__ outp,
                                              const int* __restrict__ rs,
                                              const int* __restrict__ csr_src,
                                              const float* __restrict__ dinv,
                                              int n_nodes, int U) {
    int idx = blockIdx.x * 256 + threadIdx.x;
    int node = idx >> 3;
    int lane = idx & 7;
    if (node >= n_nodes) return;
    int e0 = rs[node], e1 = rs[node + 1];
    float dn = dinv[node];
    float s0 = 0.f, s1 = 0.f, s2 = 0.f, s3 = 0.f;
    float s4 = 0.f, s5 = 0.f, s6 = 0.f, s7 = 0.f;
    int em = e1 - 1;
    for (int ep = e0; ep < e1; ep += 4) GATHER4(x3, ep, em, dn)
    uint4 v1 = x1[(size_t)node * 8 + lane];
    uint4 v2 = x2[(size_t)node * 8 + lane];
    uint4 v3 = x3[(size_t)node * 8 + lane];
    const float* ebp = (node < U) ? (embU + (size_t)node * EMB_D)
                                  : (embI + (size_t)(node - U) * EMB_D);
    float4 ea = ((const float4*)ebp)[lane * 2];
    float4 eb2 = ((const float4*)ebp)[lane * 2 + 1];
    const float sc = 1.0f / 25.0f;
    float4 o0, o1;
    o0.x = (ea.x  + bflo(v1.x) + bflo(v2.x) + bflo(v3.x) + s0) * sc;
    o0.y = (ea.y  + bfhi(v1.x) + bfhi(v2.x) + bfhi(v3.x) + s1) * sc;
    o0.z = (ea.z  + bflo(v1.y) + bflo(v2.y) + bflo(v3.y) + s2) * sc;
    o0.w = (ea.w  + bfhi(v1.y) + bfhi(v2.y) + bfhi(v3.y) + s3) * sc;
    o1.x = (eb2.x + bflo(v1.z) + bflo(v2.z) + bflo(v3.z) + s4) * sc;
    o1.y = (eb2.y + bfhi(v1.z) + bfhi(v2.z) + bfhi(v3.z) + s5) * sc;
    o1.z = (eb2.z + bflo(v1.w) + bflo(v2.w) + bflo(v3.w) + s6) * sc;
    o1.w = (eb2.w + bfhi(v1.w) + bfhi(v2.w) + bfhi(v3.w) + s7) * sc;
    float4* op = (float4*)(outp + (size_t)node * EMB_D) + lane * 2;
    op[0] = o0;
    op[1] = o1;
}

// ---------------------------------------------------------------------------
// Projection via MFMA bf16: out[r][c] += (F @ W^T)[r][c]   (sum/25 already in out)
// 256 threads = 4 waves/block; wave owns 16 rows x 64 cols. All 16 A float4
// loads are forced co-resident by a SINGLE asm barrier depending on all 16
// (R10 lesson: per-load keep-alives only order the asms -> compiler emitted
// load;keep;load;keep serial chain, VGPR=60 < 64 proved it). W in LDS.
// Fragment layouts (16x16x32 bf16, m89/m91-verified):
//   A: row = l&15, k = (l>>4)*8 + j ;  B: col = l&15, k = (l>>4)*8 + j
//   D: col = l&15, row = (l>>4)*4 + reg
__global__ __launch_bounds__(256) void k_projm(const float* __restrict__ FU,
                                               const float* __restrict__ FI,
                                               const unsigned short* __restrict__ WUb,
                                               const unsigned short* __restrict__ WIb,
                                               float* __restrict__ out,
                                               int nbU, int U, int I) {
    __shared__ uint4 sB[2048];   // 32 KB: [kk(32)][nt(4)][c(16)]
    const bool isU = ((int)blockIdx.x < nbU);
    const uint4* __restrict__ Wb4 = (const uint4*)(isU ? WUb : WIb);
    #pragma unroll
    for (int i = 0; i < 8; ++i) {
        int d = threadIdx.x + i * 256;          // 0..2047
        int kk = d >> 6, nt = (d >> 4) & 3, c = d & 15;
        sB[d] = Wb4[(size_t)(nt * 16 + c) * 32 + kk];
    }

    const float* __restrict__ F = isU ? FU : FI;
    float* __restrict__ o = isU ? out : out + (size_t)U * EMB_D;
    const int M = isU ? U : I;
    const int wave = threadIdx.x >> 6;           // 0..3
    const int lane = threadIdx.x & 63;
    const int l15  = lane & 15;
    const int kq   = lane >> 4;
    const int row0 = (isU ? (int)blockIdx.x : (int)blockIdx.x - nbU) * 64 + wave * 16;
    const int arow = min(row0 + l15, M - 1);     // clamp: dup rows, discarded at store
    const float* fb = F + (size_t)arow * FEAT_K + kq * 8;

    // issue ALL 16 A loads; ONE asm barrier depending on all of them forces
    // them to be issued together (16 outstanding) and complete here.
    float4 a0 = ((const float4*)(fb +   0))[0], a1 = ((const float4*)(fb +   0))[1];
    float4 a2 = ((const float4*)(fb +  32))[0], a3 = ((const float4*)(fb +  32))[1];
    float4 a4 = ((const float4*)(fb +  64))[0], a5 = ((const float4*)(fb +  64))[1];
    float4 a6 = ((const float4*)(fb +  96))[0], a7 = ((const float4*)(fb +  96))[1];
    float4 a8 = ((const float4*)(fb + 128))[0], a9 = ((const float4*)(fb + 128))[1];
    float4 aa = ((const float4*)(fb + 160))[0], ab = ((const float4*)(fb + 160))[1];
    float4 ac = ((const float4*)(fb + 192))[0], ad = ((const float4*)(fb + 192))[1];
    float4 ae = ((const float4*)(fb + 224))[0], af = ((const float4*)(fb + 224))[1];
    asm volatile(""
        : "+v"(a0.x), "+v"(a1.x), "+v"(a2.x), "+v"(a3.x),
          "+v"(a4.x), "+v"(a5.x), "+v"(a6.x), "+v"(a7.x),
          "+v"(a8.x), "+v"(a9.x), "+v"(aa.x), "+v"(ab.x),
          "+v"(ac.x), "+v"(ad.x), "+v"(ae.x), "+v"(af.x));

    __syncthreads();

    f32x4 acc0 = {0.f, 0.f, 0.f, 0.f};
    f32x4 acc1 = {0.f, 0.f, 0.f, 0.f};
    f32x4 acc2 = {0.f, 0.f, 0.f, 0.f};
    f32x4 acc3 = {0.f, 0.f, 0.f, 0.f};

#define CVT2(d_, lo_, hi_) asm("v_cvt_pk_bf16_f32 %0, %1, %2" : "=v"(d_) : "v"(lo_), "v"(hi_))
#define KSTEP(ks_, xa_, ya_)                                                   \
    {                                                                          \
        unsigned p0, p1, p2, p3;                                               \
        CVT2(p0, (xa_).x, (xa_).y); CVT2(p1, (xa_).z, (xa_).w);                \
        CVT2(p2, (ya_).x, (ya_).y); CVT2(p3, (ya_).z, (ya_).w);                \
        uint4 up; up.x = p0; up.y = p1; up.z = p2; up.w = p3;                  \
        short8 av = __builtin_bit_cast(short8, up);                            \
        const uint4* sbk = &sB[((ks_) * 4 + kq) * 64];                         \
        short8 b0 = __builtin_bit_cast(short8, sbk[l15]);                      \
        short8 b1 = __builtin_bit_cast(short8, sbk[16 + l15]);                 \
        short8 b2 = __builtin_bit_cast(short8, sbk[32 + l15]);                 \
        short8 b3 = __builtin_bit_cast(short8, sbk[48 + l15]);                 \
        acc0 = __builtin_amdgcn_mfma_f32_16x16x32_bf16(av, b0, acc0, 0, 0, 0); \
        acc1 = __builtin_amdgcn_mfma_f32_16x16x32_bf16(av, b1, acc1, 0, 0, 0); \
        acc2 = __builtin_amdgcn_mfma_f32_16x16x32_bf16(av, b2, acc2, 0, 0, 0); \
        acc3 = __builtin_amdgcn_mfma_f32_16x16x32_bf16(av, b3, acc3, 0, 0, 0); \
    }

    KSTEP(0, a0, a1) KSTEP(1, a2, a3) KSTEP(2, a4, a5) KSTEP(3, a6, a7)
    KSTEP(4, a8, a9) KSTEP(5, aa, ab) KSTEP(6, ac, ad) KSTEP(7, ae, af)
#undef KSTEP
#undef CVT2

    #pragma unroll
    for (int r = 0; r < 4; ++r) {
        int grow = row0 + kq * 4 + r;
        if (grow < M) {
            float* op = o + (size_t)grow * EMB_D + l15;
            op[0]  += acc0[r];
            op[16] += acc1[r];
            op[32] += acc2[r];
            op[48] += acc3[r];
        }
    }
}

// ---------------------------------------------------------------------------
extern "C" void kernel_launch(void* const* d_in, const int* in_sizes, int n_in,
                              void* d_out, int out_size, void* d_ws, size_t ws_size,
                              hipStream_t stream) {
    const int E = in_sizes[0] / 2;
    const int N = N_NODES, U = U_NODES;

    const int*   edge  = (const int*)d_in[0];
    const float* emb_u = (const float*)d_in[1];
    const float* emb_i = (const float*)d_in[2];
    const float* fu    = (const float*)d_in[3];
    const float* fi    = (const float*)d_in[4];
    const float* wu    = (const float*)d_in[5];
    const float* wi    = (const float*)d_in[6];
    const int* row = edge;
    const int* col = edge + E;

    const int NB  = (N + 255) / 256;
    const int EB  = (E + 255) / 256;
    const int XB8 = ((N * 8) + 255) / 256;

    // Workspace carve (aligned 256B). ~84 MB total.
    char* p = (char*)d_ws;
    auto carve = [&](size_t bytes) -> void* {
        void* q = (void*)p;
        p += (bytes + 255) & ~(size_t)255;
        return q;
    };
    float* dinv    = (float*)carve((size_t)N * 4);
    int*   deg     = (int*)  carve((size_t)N * 4);
    int*   rs      = (int*)  carve((size_t)(N + 1) * 4);
    int*   cursor  = (int*)  carve((size_t)N * 4);
    int*   bsum    = (int*)  carve(1024 * 4);
    int*   csr_src = (int*)  carve((size_t)E * 4);      // src index only (4B/edge)
    unsigned short* wub = (unsigned short*)carve((size_t)EMB_D * FEAT_K * 2);
    unsigned short* wib = (unsigned short*)carve((size_t)EMB_D * FEAT_K * 2);
    uint4* x0 = (uint4*)carve((size_t)N * EMB_D * 2);   // bf16 layer states
    uint4* x1 = (uint4*)carve((size_t)N * EMB_D * 2);
    uint4* x2 = (uint4*)carve((size_t)N * EMB_D * 2);
    uint4* x3 = (uint4*)carve((size_t)N * EMB_D * 2);

    float* outp = (float*)d_out;   // [N][64] == [u_final; i_final]

    hipMemsetAsync(deg, 0, (size_t)N * 4, stream);
    k_count<<<EB, 256, 0, stream>>>(col, deg, E);
    k_dinv<<<NB, 256, 0, stream>>>(deg, dinv, N);
    k_scan_a<<<NB, 256, 0, stream>>>(deg, rs, bsum, N);
    k_scan_b<<<1, 1024, 0, stream>>>(bsum, NB);
    k_scan_c<<<NB, 256, 0, stream>>>(rs, bsum, cursor, N, E);
    k_fill<<<EB, 256, 0, stream>>>(row, col, cursor, csr_src, E);
    k_cvtw<<<(2 * EMB_D * FEAT_K) / 256, 256, 0, stream>>>(wu, wi, wub, wib);
    k_init<<<XB8, 256, 0, stream>>>((const float4*)emb_u, (const float4*)emb_i,
                                    x0, U * 8, N * 8);
    // layers 1..3: pure propagation, bf16 state
    k_agg<<<XB8, 256, 0, stream>>>(x0, x1, rs, csr_src, dinv, N);
    k_agg<<<XB8, 256, 0, stream>>>(x1, x2, rs, csr_src, dinv, N);
    k_agg<<<XB8, 256, 0, stream>>>(x2, x3, rs, csr_src, dinv, N);
    // layer 4 fused with the (x0..x4) sum and 1/25 scale -> d_out
    k_agg4<<<XB8, 256, 0, stream>>>(x3, x1, x2, emb_u, emb_i, outp, rs, csr_src, dinv, N, U);
    // projection: out += F @ W^T (user + item in one launch)
    const int nbU = (U + 63) / 64;               // 1563
    const int nbI = (N - U + 63) / 64;           // 782
    k_projm<<<nbU + nbI, 256, 0, stream>>>(fu, fi, wub, wib, outp, nbU, U, N - U);
}

// Round 12
// 282.503 us; speedup vs baseline: 1.1219x; 1.1219x over previous
//
#include <hip/hip_runtime.h>

// Problem constants (match reference)
#define U_NODES 100000
#define I_NODES 50000
#define N_NODES 150000   // U + I
#define EMB_D   64
#define FEAT_K  256
#define N_LAYERS 4

typedef __attribute__((ext_vector_type(8))) short short8;
typedef __attribute__((ext_vector_type(4))) float f32x4;

// f32 -> bf16 round-to-nearest-even (bit trick)
static __device__ __forceinline__ unsigned short f2bf(float f) {
    unsigned u = __builtin_bit_cast(unsigned, f);
    u += 0x7fffu + ((u >> 16) & 1u);
    return (unsigned short)(u >> 16);
}
static __device__ __forceinline__ float bflo(unsigned u) {
    return __builtin_bit_cast(float, u << 16);
}
static __device__ __forceinline__ float bfhi(unsigned u) {
    return __builtin_bit_cast(float, u & 0xffff0000u);
}

// ---------------------------------------------------------------------------
__global__ __launch_bounds__(256) void k_count(const int* __restrict__ col,
                                               int* __restrict__ deg, int E) {
    int e = blockIdx.x * 256 + threadIdx.x;
    if (e < E) atomicAdd(&deg[col[e]], 1);
}

__global__ __launch_bounds__(256) void k_dinv(const int* __restrict__ deg,
                                              float* __restrict__ dinv, int n) {
    int i = blockIdx.x * 256 + threadIdx.x;
    if (i < n) {
        int d = deg[i];
        dinv[i] = (d > 0) ? rsqrtf((float)d) : 0.0f;
    }
}

__global__ __launch_bounds__(256) void k_scan_a(const int* __restrict__ deg,
                                                int* __restrict__ rs,
                                                int* __restrict__ bsum, int n) {
    __shared__ int wsum[4];
    int t = threadIdx.x;
    int i = blockIdx.x * 256 + t;
    int v = (i < n) ? deg[i] : 0;
    int x = v;
    #pragma unroll
    for (int off = 1; off < 64; off <<= 1) {
        int y = __shfl_up(x, off, 64);
        if ((t & 63) >= off) x += y;
    }
    if ((t & 63) == 63) wsum[t >> 6] = x;
    __syncthreads();
    int base = 0;
    #pragma unroll
    for (int w = 0; w < 4; ++w) base += (w < (t >> 6)) ? wsum[w] : 0;
    if (i < n) rs[i] = base + x - v;
    if (t == 255) bsum[blockIdx.x] = base + x;
}

__global__ __launch_bounds__(1024) void k_scan_b(int* __restrict__ bs, int nb) {
    __shared__ int wsum[16];
    int t = threadIdx.x;
    int v = (t < nb) ? bs[t] : 0;
    int x = v;
    #pragma unroll
    for (int off = 1; off < 64; off <<= 1) {
        int y = __shfl_up(x, off, 64);
        if ((t & 63) >= off) x += y;
    }
    if ((t & 63) == 63) wsum[t >> 6] = x;
    __syncthreads();
    int base = 0;
    #pragma unroll
    for (int w = 0; w < 16; ++w) base += (w < (t >> 6)) ? wsum[w] : 0;
    if (t < nb) bs[t] = base + x - v;
}

__global__ __launch_bounds__(256) void k_scan_c(int* __restrict__ rs,
                                                const int* __restrict__ bsum,
                                                int* __restrict__ cursor,
                                                int n, int E) {
    int i = blockIdx.x * 256 + threadIdx.x;
    if (i < n) {
        int v = rs[i] + bsum[blockIdx.x];
        rs[i] = v;
        cursor[i] = v;
    }
    if (i == 0) rs[n] = E;
}

// CSR fill, DESTINATION-PARTITIONED: this launch only scatters edges whose
// dst falls in [lo, hi). The scatter region rs[lo]..rs[hi] is ~2 MB and all
// ~8 writes per cache line land within this launch -> ~1 writeback/line
// (R11 lesson: payload size didn't matter, WRITE_SIZE is line-granular;
// temporal clustering of the target region is the only fix).
__global__ __launch_bounds__(256) void k_fill(const int* __restrict__ row,
                                              const int* __restrict__ col,
                                              const float* __restrict__ dinv,
                                              int* __restrict__ cursor,
                                              int2* __restrict__ csr, int E,
                                              int lo, int hi) {
    int e = blockIdx.x * 256 + threadIdx.x;
    if (e < E) {
        int c = col[e];
        if (c >= lo && c < hi) {
            int r = row[e];
            int p = atomicAdd(&cursor[c], 1);
            int2 v;
            v.x = r;
            v.y = __builtin_bit_cast(int, dinv[r] * dinv[c]);
            csr[p] = v;
        }
    }
}

// Convert W matrices to bf16 (once per call; 32K elements total)
__global__ __launch_bounds__(256) void k_cvtw(const float* __restrict__ wu,
                                              const float* __restrict__ wi,
                                              unsigned short* __restrict__ wub,
                                              unsigned short* __restrict__ wib) {
    int i = blockIdx.x * 256 + threadIdx.x;
    if (i < EMB_D * FEAT_K) wub[i] = f2bf(wu[i]);
    else                    wib[i - EMB_D * FEAT_K] = f2bf(wi[i - EMB_D * FEAT_K]);
}

// Init: x0 (bf16) = concat(emb_users, emb_items). One thread per 8 elements.
__global__ __launch_bounds__(256) void k_init(const float4* __restrict__ eu,
                                              const float4* __restrict__ ei,
                                              uint4* __restrict__ x,
                                              int n8u, int n8) {
    int i = blockIdx.x * 256 + threadIdx.x;
    if (i >= n8) return;
    const float4* s = (i < n8u) ? (eu + (size_t)i * 2) : (ei + (size_t)(i - n8u) * 2);
    float4 p0 = s[0], p1 = s[1];
    uint4 r;
    r.x = (unsigned)f2bf(p0.x) | ((unsigned)f2bf(p0.y) << 16);
    r.y = (unsigned)f2bf(p0.z) | ((unsigned)f2bf(p0.w) << 16);
    r.z = (unsigned)f2bf(p1.x) | ((unsigned)f2bf(p1.y) << 16);
    r.w = (unsigned)f2bf(p1.z) | ((unsigned)f2bf(p1.w) << 16);
    x[i] = r;
}

// NOTE: macro params use trailing-underscore names (R5 lesson: never collide
// with .x/.y/.z/.w member tokens).
#define ACC8(v_, w_)                       \
    s0 = fmaf(bflo((v_).x), (w_), s0);     \
    s1 = fmaf(bfhi((v_).x), (w_), s1);     \
    s2 = fmaf(bflo((v_).y), (w_), s2);     \
    s3 = fmaf(bfhi((v_).y), (w_), s3);     \
    s4 = fmaf(bflo((v_).z), (w_), s4);     \
    s5 = fmaf(bfhi((v_).z), (w_), s5);     \
    s6 = fmaf(bflo((v_).w), (w_), s6);     \
    s7 = fmaf(bfhi((v_).w), (w_), s7);

// Masked 4-wide gather round: always 4 outstanding gathers; OOB lanes are
// clamped to the last edge with weight zeroed.
#define GATHER4(xsrc_, ep_, em_)                                              \
    {                                                                         \
        int i0_ = (ep_), i1_ = min((ep_) + 1, (em_));                         \
        int i2_ = min((ep_) + 2, (em_)), i3_ = min((ep_) + 3, (em_));         \
        int2 pa_ = csr[i0_], pb_ = csr[i1_], pc_ = csr[i2_], pd_ = csr[i3_];  \
        float wa_ = __builtin_bit_cast(float, pa_.y);                         \
        float wb_ = ((ep_) + 1 <= (em_)) ? __builtin_bit_cast(float, pb_.y) : 0.f; \
        float wc_ = ((ep_) + 2 <= (em_)) ? __builtin_bit_cast(float, pc_.y) : 0.f; \
        float wd_ = ((ep_) + 3 <= (em_)) ? __builtin_bit_cast(float, pd_.y) : 0.f; \
        uint4 va_ = (xsrc_)[(size_t)pa_.x * 8 + lane];                        \
        uint4 vb_ = (xsrc_)[(size_t)pb_.x * 8 + lane];                        \
        uint4 vc_ = (xsrc_)[(size_t)pc_.x * 8 + lane];                        \
        uint4 vd_ = (xsrc_)[(size_t)pd_.x * 8 + lane];                        \
        ACC8(va_, wa_) ACC8(vb_, wb_) ACC8(vc_, wc_) ACC8(vd_, wd_)           \
    }

// Pull-mode aggregation (layers 1..3), bf16 state: 8 lanes/node, 16B/lane.
__global__ __launch_bounds__(256) void k_agg(const uint4* __restrict__ xin,
                                             uint4* __restrict__ xout,
                                             const int* __restrict__ rs,
                                             const int2* __restrict__ csr,
                                             int n_nodes) {
    int idx = blockIdx.x * 256 + threadIdx.x;
    int node = idx >> 3;
    int lane = idx & 7;
    if (node >= n_nodes) return;
    int e0 = rs[node], e1 = rs[node + 1];
    float s0 = 0.f, s1 = 0.f, s2 = 0.f, s3 = 0.f;
    float s4 = 0.f, s5 = 0.f, s6 = 0.f, s7 = 0.f;
    int em = e1 - 1;
    for (int ep = e0; ep < e1; ep += 4) GATHER4(xin, ep, em)
    uint4 r;
    r.x = (unsigned)f2bf(s0) | ((unsigned)f2bf(s1) << 16);
    r.y = (unsigned)f2bf(s2) | ((unsigned)f2bf(s3) << 16);
    r.z = (unsigned)f2bf(s4) | ((unsigned)f2bf(s5) << 16);
    r.w = (unsigned)f2bf(s6) | ((unsigned)f2bf(s7) << 16);
    xout[(size_t)node * 8 + lane] = r;
}

// Layer 4 + fused sum: s = gather(x3); out_row = (emb + x1 + x2 + x3 + s)/25
__global__ __launch_bounds__(256) void k_agg4(const uint4* __restrict__ x3,
                                              const uint4* __restrict__ x1,
                                              const uint4* __restrict__ x2,
                                              const float* __restrict__ embU,
                                              const float* __restrict__ embI,
                                              float* __restrict__ outp,
                                              const int* __restrict__ rs,
                                              const int2* __restrict__ csr,
                                              int n_nodes, int U) {
    int idx = blockIdx.x * 256 + threadIdx.x;
    int node = idx >> 3;
    int lane = idx & 7;
    if (node >= n_nodes) return;
    int e0 = rs[node], e1 = rs[node + 1];
    float s0 = 0.f, s1 = 0.f, s2 = 0.f, s3 = 0.f;
    float s4 = 0.f, s5 = 0.f, s6 = 0.f, s7 = 0.f;
    int em = e1 - 1;
    for (int ep = e0; ep < e1; ep += 4) GATHER4(x3, ep, em)
    uint4 v1 = x1[(size_t)node * 8 + lane];
    uint4 v2 = x2[(size_t)node * 8 + lane];
    uint4 v3 = x3[(size_t)node * 8 + lane];
    const float* ebp = (node < U) ? (embU + (size_t)node * EMB_D)
                                  : (embI + (size_t)(node - U) * EMB_D);
    float4 ea = ((const float4*)ebp)[lane * 2];
    float4 eb2 = ((const float4*)ebp)[lane * 2 + 1];
    const float sc = 1.0f / 25.0f;
    float4 o0, o1;
    o0.x = (ea.x  + bflo(v1.x) + bflo(v2.x) + bflo(v3.x) + s0) * sc;
    o0.y = (ea.y  + bfhi(v1.x) + bfhi(v2.x) + bfhi(v3.x) + s1) * sc;
    o0.z = (ea.z  + bflo(v1.y) + bflo(v2.y) + bflo(v3.y) + s2) * sc;
    o0.w = (ea.w  + bfhi(v1.y) + bfhi(v2.y) + bfhi(v3.y) + s3) * sc;
    o1.x = (eb2.x + bflo(v1.z) + bflo(v2.z) + bflo(v3.z) + s4) * sc;
    o1.y = (eb2.y + bfhi(v1.z) + bfhi(v2.z) + bfhi(v3.z) + s5) * sc;
    o1.z = (eb2.z + bflo(v1.w) + bflo(v2.w) + bflo(v3.w) + s6) * sc;
    o1.w = (eb2.w + bfhi(v1.w) + bfhi(v2.w) + bfhi(v3.w) + s7) * sc;
    float4* op = (float4*)(outp + (size_t)node * EMB_D) + lane * 2;
    op[0] = o0;
    op[1] = o1;
}

// ---------------------------------------------------------------------------
// Projection via MFMA bf16: out[r][c] += (F @ W^T)[r][c]   (sum/25 already in out)
// 256 threads = 4 waves/block; wave owns 16 rows x 64 cols; 16 A float4 loads
// up-front. __launch_bounds__(256, 1) lifts the VGPR cap (R9/R10 lesson:
// VGPR_Count 48/60 < 64 proved the allocator was capping registers for
// occupancy and SINKING the loads into a serial chain; asm hacks fought the
// scheduler, this fixes the budget). Compiler then hoists all 16 loads and
// emits fine-grained vmcnt waits per KSTEP. W staged once in LDS [kk][nt][c].
// Fragment layouts (16x16x32 bf16, m89/m91-verified):
//   A: row = l&15, k = (l>>4)*8 + j ;  B: col = l&15, k = (l>>4)*8 + j
//   D: col = l&15, row = (l>>4)*4 + reg
__global__ __launch_bounds__(256, 1) void k_projm(const float* __restrict__ FU,
                                               const float* __restrict__ FI,
                                               const unsigned short* __restrict__ WUb,
                                               const unsigned short* __restrict__ WIb,
                                               float* __restrict__ out,
                                               int nbU, int U, int I) {
    __shared__ uint4 sB[2048];   // 32 KB: [kk(32)][nt(4)][c(16)]
    const bool isU = ((int)blockIdx.x < nbU);
    const uint4* __restrict__ Wb4 = (const uint4*)(isU ? WUb : WIb);
    #pragma unroll
    for (int i = 0; i < 8; ++i) {
        int d = threadIdx.x + i * 256;          // 0..2047
        int kk = d >> 6, nt = (d >> 4) & 3, c = d & 15;
        sB[d] = Wb4[(size_t)(nt * 16 + c) * 32 + kk];
    }

    const float* __restrict__ F = isU ? FU : FI;
    float* __restrict__ o = isU ? out : out + (size_t)U * EMB_D;
    const int M = isU ? U : I;
    const int wave = threadIdx.x >> 6;           // 0..3
    const int lane = threadIdx.x & 63;
    const int l15  = lane & 15;
    const int kq   = lane >> 4;
    const int row0 = (isU ? (int)blockIdx.x : (int)blockIdx.x - nbU) * 64 + wave * 16;
    const int arow = min(row0 + l15, M - 1);     // clamp: dup rows, discarded at store
    const float* fb = F + (size_t)arow * FEAT_K + kq * 8;

    // issue ALL 16 A loads up-front (VGPR budget unconstrained -> co-resident)
    float4 a0 = ((const float4*)(fb +   0))[0], a1 = ((const float4*)(fb +   0))[1];
    float4 a2 = ((const float4*)(fb +  32))[0], a3 = ((const float4*)(fb +  32))[1];
    float4 a4 = ((const float4*)(fb +  64))[0], a5 = ((const float4*)(fb +  64))[1];
    float4 a6 = ((const float4*)(fb +  96))[0], a7 = ((const float4*)(fb +  96))[1];
    float4 a8 = ((const float4*)(fb + 128))[0], a9 = ((const float4*)(fb + 128))[1];
    float4 aa = ((const float4*)(fb + 160))[0], ab = ((const float4*)(fb + 160))[1];
    float4 ac = ((const float4*)(fb + 192))[0], ad = ((const float4*)(fb + 192))[1];
    float4 ae = ((const float4*)(fb + 224))[0], af = ((const float4*)(fb + 224))[1];

    __syncthreads();

    f32x4 acc0 = {0.f, 0.f, 0.f, 0.f};
    f32x4 acc1 = {0.f, 0.f, 0.f, 0.f};
    f32x4 acc2 = {0.f, 0.f, 0.f, 0.f};
    f32x4 acc3 = {0.f, 0.f, 0.f, 0.f};

#define CVT2(d_, lo_, hi_) asm("v_cvt_pk_bf16_f32 %0, %1, %2" : "=v"(d_) : "v"(lo_), "v"(hi_))
#define KSTEP(ks_, xa_, ya_)                                                   \
    {                                                                          \
        unsigned p0, p1, p2, p3;                                               \
        CVT2(p0, (xa_).x, (xa_).y); CVT2(p1, (xa_).z, (xa_).w);                \
        CVT2(p2, (ya_).x, (ya_).y); CVT2(p3, (ya_).z, (ya_).w);                \
        uint4 up; up.x = p0; up.y = p1; up.z = p2; up.w = p3;                  \
        short8 av = __builtin_bit_cast(short8, up);                            \
        const uint4* sbk = &sB[((ks_) * 4 + kq) * 64];                         \
        short8 b0 = __builtin_bit_cast(short8, sbk[l15]);                      \
        short8 b1 = __builtin_bit_cast(short8, sbk[16 + l15]);                 \
        short8 b2 = __builtin_bit_cast(short8, sbk[32 + l15]);                 \
        short8 b3 = __builtin_bit_cast(short8, sbk[48 + l15]);                 \
        acc0 = __builtin_amdgcn_mfma_f32_16x16x32_bf16(av, b0, acc0, 0, 0, 0); \
        acc1 = __builtin_amdgcn_mfma_f32_16x16x32_bf16(av, b1, acc1, 0, 0, 0); \
        acc2 = __builtin_amdgcn_mfma_f32_16x16x32_bf16(av, b2, acc2, 0, 0, 0); \
        acc3 = __builtin_amdgcn_mfma_f32_16x16x32_bf16(av, b3, acc3, 0, 0, 0); \
    }

    KSTEP(0, a0, a1) KSTEP(1, a2, a3) KSTEP(2, a4, a5) KSTEP(3, a6, a7)
    KSTEP(4, a8, a9) KSTEP(5, aa, ab) KSTEP(6, ac, ad) KSTEP(7, ae, af)
#undef KSTEP
#undef CVT2

    #pragma unroll
    for (int r = 0; r < 4; ++r) {
        int grow = row0 + kq * 4 + r;
        if (grow < M) {
            float* op = o + (size_t)grow * EMB_D + l15;
            op[0]  += acc0[r];
            op[16] += acc1[r];
            op[32] += acc2[r];
            op[48] += acc3[r];
        }
    }
}

// ---------------------------------------------------------------------------
extern "C" void kernel_launch(void* const* d_in, const int* in_sizes, int n_in,
                              void* d_out, int out_size, void* d_ws, size_t ws_size,
                              hipStream_t stream) {
    const int E = in_sizes[0] / 2;
    const int N = N_NODES, U = U_NODES;

    const int*   edge  = (const int*)d_in[0];
    const float* emb_u = (const float*)d_in[1];
    const float* emb_i = (const float*)d_in[2];
    const float* fu    = (const float*)d_in[3];
    const float* fi    = (const float*)d_in[4];
    const float* wu    = (const float*)d_in[5];
    const float* wi    = (const float*)d_in[6];
    const int* row = edge;
    const int* col = edge + E;

    const int NB  = (N + 255) / 256;
    const int EB  = (E + 255) / 256;
    const int XB8 = ((N * 8) + 255) / 256;

    // Workspace carve (aligned 256B). ~88 MB total.
    char* p = (char*)d_ws;
    auto carve = [&](size_t bytes) -> void* {
        void* q = (void*)p;
        p += (bytes + 255) & ~(size_t)255;
        return q;
    };
    float* dinv    = (float*)carve((size_t)N * 4);
    int*   deg     = (int*)  carve((size_t)N * 4);
    int*   rs      = (int*)  carve((size_t)(N + 1) * 4);
    int*   cursor  = (int*)  carve((size_t)N * 4);
    int*   bsum    = (int*)  carve(1024 * 4);
    int2*  csr     = (int2*) carve((size_t)E * 8);      // packed (src, norm)
    unsigned short* wub = (unsigned short*)carve((size_t)EMB_D * FEAT_K * 2);
    unsigned short* wib = (unsigned short*)carve((size_t)EMB_D * FEAT_K * 2);
    uint4* x0 = (uint4*)carve((size_t)N * EMB_D * 2);   // bf16 layer states
    uint4* x1 = (uint4*)carve((size_t)N * EMB_D * 2);
    uint4* x2 = (uint4*)carve((size_t)N * EMB_D * 2);
    uint4* x3 = (uint4*)carve((size_t)N * EMB_D * 2);

    float* outp = (float*)d_out;   // [N][64] == [u_final; i_final]

    hipMemsetAsync(deg, 0, (size_t)N * 4, stream);
    k_count<<<EB, 256, 0, stream>>>(col, deg, E);
    k_dinv<<<NB, 256, 0, stream>>>(deg, dinv, N);
    k_scan_a<<<NB, 256, 0, stream>>>(deg, rs, bsum, N);
    k_scan_b<<<1, 1024, 0, stream>>>(bsum, NB);
    k_scan_c<<<NB, 256, 0, stream>>>(rs, bsum, cursor, N, E);
    // dst-partitioned CSR fill: 4 launches, each scatters only its N/4 range
    // (2 MB L2-resident target region -> ~1 writeback per line)
    {
        const int P = 4;
        for (int pp = 0; pp < P; ++pp) {
            int lo = (int)(((long long)N * pp) / P);
            int hi = (int)(((long long)N * (pp + 1)) / P);
            k_fill<<<EB, 256, 0, stream>>>(row, col, dinv, cursor, csr, E, lo, hi);
        }
    }
    k_cvtw<<<(2 * EMB_D * FEAT_K) / 256, 256, 0, stream>>>(wu, wi, wub, wib);
    k_init<<<XB8, 256, 0, stream>>>((const float4*)emb_u, (const float4*)emb_i,
                                    x0, U * 8, N * 8);
    // layers 1..3: pure propagation, bf16 state
    k_agg<<<XB8, 256, 0, stream>>>(x0, x1, rs, csr, N);
    k_agg<<<XB8, 256, 0, stream>>>(x1, x2, rs, csr, N);
    k_agg<<<XB8, 256, 0, stream>>>(x2, x3, rs, csr, N);
    // layer 4 fused with the (x0..x4) sum and 1/25 scale -> d_out
    k_agg4<<<XB8, 256, 0, stream>>>(x3, x1, x2, emb_u, emb_i, outp, rs, csr, N, U);
    // projection: out += F @ W^T (user + item in one launch)
    const int nbU = (U + 63) / 64;               // 1563
    const int nbI = (N - U + 63) / 64;           // 782
    k_projm<<<nbU + nbI, 256, 0, stream>>>(fu, fi, wub, wib, outp, nbU, U, N - U);
}

// Round 13
// 280.864 us; speedup vs baseline: 1.1285x; 1.0058x over previous
//
#include <hip/hip_runtime.h>

// Problem constants (match reference)
#define U_NODES 100000
#define I_NODES 50000
#define N_NODES 150000   // U + I
#define EMB_D   64
#define FEAT_K  256
#define N_LAYERS 4

typedef __attribute__((ext_vector_type(8))) short short8;
typedef __attribute__((ext_vector_type(4))) float f32x4;

// f32 -> bf16 round-to-nearest-even (bit trick)
static __device__ __forceinline__ unsigned short f2bf(float f) {
    unsigned u = __builtin_bit_cast(unsigned, f);
    u += 0x7fffu + ((u >> 16) & 1u);
    return (unsigned short)(u >> 16);
}
static __device__ __forceinline__ float bflo(unsigned u) {
    return __builtin_bit_cast(float, u << 16);
}
static __device__ __forceinline__ float bfhi(unsigned u) {
    return __builtin_bit_cast(float, u & 0xffff0000u);
}

// ---------------------------------------------------------------------------
__global__ __launch_bounds__(256) void k_count(const int* __restrict__ col,
                                               int* __restrict__ deg, int E) {
    int e = blockIdx.x * 256 + threadIdx.x;
    if (e < E) atomicAdd(&deg[col[e]], 1);
}

__global__ __launch_bounds__(256) void k_dinv(const int* __restrict__ deg,
                                              float* __restrict__ dinv, int n) {
    int i = blockIdx.x * 256 + threadIdx.x;
    if (i < n) {
        int d = deg[i];
        dinv[i] = (d > 0) ? rsqrtf((float)d) : 0.0f;
    }
}

__global__ __launch_bounds__(256) void k_scan_a(const int* __restrict__ deg,
                                                int* __restrict__ rs,
                                                int* __restrict__ bsum, int n) {
    __shared__ int wsum[4];
    int t = threadIdx.x;
    int i = blockIdx.x * 256 + t;
    int v = (i < n) ? deg[i] : 0;
    int x = v;
    #pragma unroll
    for (int off = 1; off < 64; off <<= 1) {
        int y = __shfl_up(x, off, 64);
        if ((t & 63) >= off) x += y;
    }
    if ((t & 63) == 63) wsum[t >> 6] = x;
    __syncthreads();
    int base = 0;
    #pragma unroll
    for (int w = 0; w < 4; ++w) base += (w < (t >> 6)) ? wsum[w] : 0;
    if (i < n) rs[i] = base + x - v;
    if (t == 255) bsum[blockIdx.x] = base + x;
}

__global__ __launch_bounds__(1024) void k_scan_b(int* __restrict__ bs, int nb) {
    __shared__ int wsum[16];
    int t = threadIdx.x;
    int v = (t < nb) ? bs[t] : 0;
    int x = v;
    #pragma unroll
    for (int off = 1; off < 64; off <<= 1) {
        int y = __shfl_up(x, off, 64);
        if ((t & 63) >= off) x += y;
    }
    if ((t & 63) == 63) wsum[t >> 6] = x;
    __syncthreads();
    int base = 0;
    #pragma unroll
    for (int w = 0; w < 16; ++w) base += (w < (t >> 6)) ? wsum[w] : 0;
    if (t < nb) bs[t] = base + x - v;
}

__global__ __launch_bounds__(256) void k_scan_c(int* __restrict__ rs,
                                                const int* __restrict__ bsum,
                                                int* __restrict__ cursor,
                                                int n, int E) {
    int i = blockIdx.x * 256 + threadIdx.x;
    if (i < n) {
        int v = rs[i] + bsum[blockIdx.x];
        rs[i] = v;
        cursor[i] = v;
    }
    if (i == 0) rs[n] = E;
}

// CSR fill: ONE scattered 8B nontemporal write per edge (src, norm packed).
// Single launch (R12 lesson: 4-way dst-partitioning cost 4x edge rescans
// and gained nothing net).
__global__ __launch_bounds__(256) void k_fill(const int* __restrict__ row,
                                              const int* __restrict__ col,
                                              const float* __restrict__ dinv,
                                              int* __restrict__ cursor,
                                              int2* __restrict__ csr, int E) {
    int e = blockIdx.x * 256 + threadIdx.x;
    if (e < E) {
        int r = row[e], c = col[e];
        int p = atomicAdd(&cursor[c], 1);
        unsigned long long v =
            ((unsigned long long)__builtin_bit_cast(unsigned, dinv[r] * dinv[c]) << 32)
            | (unsigned)r;   // low word -> .x (src), high -> .y (nrm)
        __builtin_nontemporal_store(v, (unsigned long long*)&csr[p]);
    }
}

// Convert W matrices to bf16 (once per call; 32K elements total)
__global__ __launch_bounds__(256) void k_cvtw(const float* __restrict__ wu,
                                              const float* __restrict__ wi,
                                              unsigned short* __restrict__ wub,
                                              unsigned short* __restrict__ wib) {
    int i = blockIdx.x * 256 + threadIdx.x;
    if (i < EMB_D * FEAT_K) wub[i] = f2bf(wu[i]);
    else                    wib[i - EMB_D * FEAT_K] = f2bf(wi[i - EMB_D * FEAT_K]);
}

// Init: x0 (bf16) = concat(emb_users, emb_items). One thread per 8 elements.
__global__ __launch_bounds__(256) void k_init(const float4* __restrict__ eu,
                                              const float4* __restrict__ ei,
                                              uint4* __restrict__ x,
                                              int n8u, int n8) {
    int i = blockIdx.x * 256 + threadIdx.x;
    if (i >= n8) return;
    const float4* s = (i < n8u) ? (eu + (size_t)i * 2) : (ei + (size_t)(i - n8u) * 2);
    float4 p0 = s[0], p1 = s[1];
    uint4 r;
    r.x = (unsigned)f2bf(p0.x) | ((unsigned)f2bf(p0.y) << 16);
    r.y = (unsigned)f2bf(p0.z) | ((unsigned)f2bf(p0.w) << 16);
    r.z = (unsigned)f2bf(p1.x) | ((unsigned)f2bf(p1.y) << 16);
    r.w = (unsigned)f2bf(p1.z) | ((unsigned)f2bf(p1.w) << 16);
    x[i] = r;
}

// NOTE: macro params use trailing-underscore names (R5 lesson: never collide
// with .x/.y/.z/.w member tokens).
#define ACC8(v_, w_)                       \
    s0 = fmaf(bflo((v_).x), (w_), s0);     \
    s1 = fmaf(bfhi((v_).x), (w_), s1);     \
    s2 = fmaf(bflo((v_).y), (w_), s2);     \
    s3 = fmaf(bfhi((v_).y), (w_), s3);     \
    s4 = fmaf(bflo((v_).z), (w_), s4);     \
    s5 = fmaf(bfhi((v_).z), (w_), s5);     \
    s6 = fmaf(bflo((v_).w), (w_), s6);     \
    s7 = fmaf(bfhi((v_).w), (w_), s7);

// Masked 4-wide gather round: always 4 outstanding gathers; OOB lanes are
// clamped to the last edge with weight zeroed.
#define GATHER4(xsrc_, ep_, em_)                                              \
    {                                                                         \
        int i0_ = (ep_), i1_ = min((ep_) + 1, (em_));                         \
        int i2_ = min((ep_) + 2, (em_)), i3_ = min((ep_) + 3, (em_));         \
        int2 pa_ = csr[i0_], pb_ = csr[i1_], pc_ = csr[i2_], pd_ = csr[i3_];  \
        float wa_ = __builtin_bit_cast(float, pa_.y);                         \
        float wb_ = ((ep_) + 1 <= (em_)) ? __builtin_bit_cast(float, pb_.y) : 0.f; \
        float wc_ = ((ep_) + 2 <= (em_)) ? __builtin_bit_cast(float, pc_.y) : 0.f; \
        float wd_ = ((ep_) + 3 <= (em_)) ? __builtin_bit_cast(float, pd_.y) : 0.f; \
        uint4 va_ = (xsrc_)[(size_t)pa_.x * 8 + lane];                        \
        uint4 vb_ = (xsrc_)[(size_t)pb_.x * 8 + lane];                        \
        uint4 vc_ = (xsrc_)[(size_t)pc_.x * 8 + lane];                        \
        uint4 vd_ = (xsrc_)[(size_t)pd_.x * 8 + lane];                        \
        ACC8(va_, wa_) ACC8(vb_, wb_) ACC8(vc_, wc_) ACC8(vd_, wd_)           \
    }

// Pull-mode aggregation (layers 1..3), bf16 state: 8 lanes/node, 16B/lane.
__global__ __launch_bounds__(256) void k_agg(const uint4* __restrict__ xin,
                                             uint4* __restrict__ xout,
                                             const int* __restrict__ rs,
                                             const int2* __restrict__ csr,
                                             int n_nodes) {
    int idx = blockIdx.x * 256 + threadIdx.x;
    int node = idx >> 3;
    int lane = idx & 7;
    if (node >= n_nodes) return;
    int e0 = rs[node], e1 = rs[node + 1];
    float s0 = 0.f, s1 = 0.f, s2 = 0.f, s3 = 0.f;
    float s4 = 0.f, s5 = 0.f, s6 = 0.f, s7 = 0.f;
    int em = e1 - 1;
    for (int ep = e0; ep < e1; ep += 4) GATHER4(xin, ep, em)
    uint4 r;
    r.x = (unsigned)f2bf(s0) | ((unsigned)f2bf(s1) << 16);
    r.y = (unsigned)f2bf(s2) | ((unsigned)f2bf(s3) << 16);
    r.z = (unsigned)f2bf(s4) | ((unsigned)f2bf(s5) << 16);
    r.w = (unsigned)f2bf(s6) | ((unsigned)f2bf(s7) << 16);
    xout[(size_t)node * 8 + lane] = r;
}

// Layer 4 + fused sum: s = gather(x3); out_row = (emb + x1 + x2 + x3 + s)/25
__global__ __launch_bounds__(256) void k_agg4(const uint4* __restrict__ x3,
                                              const uint4* __restrict__ x1,
                                              const uint4* __restrict__ x2,
                                              const float* __restrict__ embU,
                                              const float* __restrict__ embI,
                                              float* __restrict__ outp,
                                              const int* __restrict__ rs,
                                              const int2* __restrict__ csr,
                                              int n_nodes, int U) {
    int idx = blockIdx.x * 256 + threadIdx.x;
    int node = idx >> 3;
    int lane = idx & 7;
    if (node >= n_nodes) return;
    int e0 = rs[node], e1 = rs[node + 1];
    float s0 = 0.f, s1 = 0.f, s2 = 0.f, s3 = 0.f;
    float s4 = 0.f, s5 = 0.f, s6 = 0.f, s7 = 0.f;
    int em = e1 - 1;
    for (int ep = e0; ep < e1; ep += 4) GATHER4(x3, ep, em)
    uint4 v1 = x1[(size_t)node * 8 + lane];
    uint4 v2 = x2[(size_t)node * 8 + lane];
    uint4 v3 = x3[(size_t)node * 8 + lane];
    const float* ebp = (node < U) ? (embU + (size_t)node * EMB_D)
                                  : (embI + (size_t)(node - U) * EMB_D);
    float4 ea = ((const float4*)ebp)[lane * 2];
    float4 eb2 = ((const float4*)ebp)[lane * 2 + 1];
    const float sc = 1.0f / 25.0f;
    float4 o0, o1;
    o0.x = (ea.x  + bflo(v1.x) + bflo(v2.x) + bflo(v3.x) + s0) * sc;
    o0.y = (ea.y  + bfhi(v1.x) + bfhi(v2.x) + bfhi(v3.x) + s1) * sc;
    o0.z = (ea.z  + bflo(v1.y) + bflo(v2.y) + bflo(v3.y) + s2) * sc;
    o0.w = (ea.w  + bfhi(v1.y) + bfhi(v2.y) + bfhi(v3.y) + s3) * sc;
    o1.x = (eb2.x + bflo(v1.z) + bflo(v2.z) + bflo(v3.z) + s4) * sc;
    o1.y = (eb2.y + bfhi(v1.z) + bfhi(v2.z) + bfhi(v3.z) + s5) * sc;
    o1.z = (eb2.z + bflo(v1.w) + bflo(v2.w) + bflo(v3.w) + s6) * sc;
    o1.w = (eb2.w + bfhi(v1.w) + bfhi(v2.w) + bfhi(v3.w) + s7) * sc;
    float4* op = (float4*)(outp + (size_t)node * EMB_D) + lane * 2;
    op[0] = o0;
    op[1] = o1;
}

// ---------------------------------------------------------------------------
// Projection via MFMA bf16: out[r][c] += (F @ W^T)[r][c]   (sum/25 already in out)
// 256 threads = 4 waves/block; wave owns 16 rows x 64 cols; 16 A f32x4 loads
// up-front, pinned by ONE asm with all 16 FULL VECTORS as "+v" operands plus
// a "memory" clobber. (R10/R12 lesson: pinning only .x let the compiler SPLIT
// each dwordx4 and sink the .yzw parts -> serial chain, VGPR 48-60. Vector
// operands can't be split; the memory clobber forbids sinking loads past it.)
// W staged once in LDS [kk][nt][c].
// Fragment layouts (16x16x32 bf16, m89/m91-verified):
//   A: row = l&15, k = (l>>4)*8 + j ;  B: col = l&15, k = (l>>4)*8 + j
//   D: col = l&15, row = (l>>4)*4 + reg
__global__ __launch_bounds__(256, 1) void k_projm(const float* __restrict__ FU,
                                               const float* __restrict__ FI,
                                               const unsigned short* __restrict__ WUb,
                                               const unsigned short* __restrict__ WIb,
                                               float* __restrict__ out,
                                               int nbU, int U, int I) {
    __shared__ uint4 sB[2048];   // 32 KB: [kk(32)][nt(4)][c(16)]
    const bool isU = ((int)blockIdx.x < nbU);
    const uint4* __restrict__ Wb4 = (const uint4*)(isU ? WUb : WIb);
    #pragma unroll
    for (int i = 0; i < 8; ++i) {
        int d = threadIdx.x + i * 256;          // 0..2047
        int kk = d >> 6, nt = (d >> 4) & 3, c = d & 15;
        sB[d] = Wb4[(size_t)(nt * 16 + c) * 32 + kk];
    }

    const float* __restrict__ F = isU ? FU : FI;
    float* __restrict__ o = isU ? out : out + (size_t)U * EMB_D;
    const int M = isU ? U : I;
    const int wave = threadIdx.x >> 6;           // 0..3
    const int lane = threadIdx.x & 63;
    const int l15  = lane & 15;
    const int kq   = lane >> 4;
    const int row0 = (isU ? (int)blockIdx.x : (int)blockIdx.x - nbU) * 64 + wave * 16;
    const int arow = min(row0 + l15, M - 1);     // clamp: dup rows, discarded at store
    const f32x4* fb = (const f32x4*)(F + (size_t)arow * FEAT_K + kq * 8);

    // issue ALL 16 A loads; the single pin-asm below forces co-residency
    f32x4 a0 = fb[ 0], a1 = fb[ 1];   // k +   0
    f32x4 a2 = fb[ 8], a3 = fb[ 9];   // k +  32
    f32x4 a4 = fb[16], a5 = fb[17];   // k +  64
    f32x4 a6 = fb[24], a7 = fb[25];   // k +  96
    f32x4 a8 = fb[32], a9 = fb[33];   // k + 128
    f32x4 aa = fb[40], ab = fb[41];   // k + 160
    f32x4 ac = fb[48], ad = fb[49];   // k + 192
    f32x4 ae = fb[56], af = fb[57];   // k + 224
    asm volatile(""
        : "+v"(a0), "+v"(a1), "+v"(a2), "+v"(a3),
          "+v"(a4), "+v"(a5), "+v"(a6), "+v"(a7),
          "+v"(a8), "+v"(a9), "+v"(aa), "+v"(ab),
          "+v"(ac), "+v"(ad), "+v"(ae), "+v"(af)
        :
        : "memory");

    __syncthreads();

    f32x4 acc0 = {0.f, 0.f, 0.f, 0.f};
    f32x4 acc1 = {0.f, 0.f, 0.f, 0.f};
    f32x4 acc2 = {0.f, 0.f, 0.f, 0.f};
    f32x4 acc3 = {0.f, 0.f, 0.f, 0.f};

#define CVT2(d_, lo_, hi_) asm("v_cvt_pk_bf16_f32 %0, %1, %2" : "=v"(d_) : "v"(lo_), "v"(hi_))
#define KSTEP(ks_, xa_, ya_)                                                   \
    {                                                                          \
        unsigned p0, p1, p2, p3;                                               \
        CVT2(p0, (xa_)[0], (xa_)[1]); CVT2(p1, (xa_)[2], (xa_)[3]);            \
        CVT2(p2, (ya_)[0], (ya_)[1]); CVT2(p3, (ya_)[2], (ya_)[3]);            \
        uint4 up; up.x = p0; up.y = p1; up.z = p2; up.w = p3;                  \
        short8 av = __builtin_bit_cast(short8, up);                            \
        const uint4* sbk = &sB[((ks_) * 4 + kq) * 64];                         \
        short8 b0 = __builtin_bit_cast(short8, sbk[l15]);                      \
        short8 b1 = __builtin_bit_cast(short8, sbk[16 + l15]);                 \
        short8 b2 = __builtin_bit_cast(short8, sbk[32 + l15]);                 \
        short8 b3 = __builtin_bit_cast(short8, sbk[48 + l15]);                 \
        acc0 = __builtin_amdgcn_mfma_f32_16x16x32_bf16(av, b0, acc0, 0, 0, 0); \
        acc1 = __builtin_amdgcn_mfma_f32_16x16x32_bf16(av, b1, acc1, 0, 0, 0); \
        acc2 = __builtin_amdgcn_mfma_f32_16x16x32_bf16(av, b2, acc2, 0, 0, 0); \
        acc3 = __builtin_amdgcn_mfma_f32_16x16x32_bf16(av, b3, acc3, 0, 0, 0); \
    }

    KSTEP(0, a0, a1) KSTEP(1, a2, a3) KSTEP(2, a4, a5) KSTEP(3, a6, a7)
    KSTEP(4, a8, a9) KSTEP(5, aa, ab) KSTEP(6, ac, ad) KSTEP(7, ae, af)
#undef KSTEP
#undef CVT2

    #pragma unroll
    for (int r = 0; r < 4; ++r) {
        int grow = row0 + kq * 4 + r;
        if (grow < M) {
            float* op = o + (size_t)grow * EMB_D + l15;
            op[0]  += acc0[r];
            op[16] += acc1[r];
            op[32] += acc2[r];
            op[48] += acc3[r];
        }
    }
}

// ---------------------------------------------------------------------------
extern "C" void kernel_launch(void* const* d_in, const int* in_sizes, int n_in,
                              void* d_out, int out_size, void* d_ws, size_t ws_size,
                              hipStream_t stream) {
    const int E = in_sizes[0] / 2;
    const int N = N_NODES, U = U_NODES;

    const int*   edge  = (const int*)d_in[0];
    const float* emb_u = (const float*)d_in[1];
    const float* emb_i = (const float*)d_in[2];
    const float* fu    = (const float*)d_in[3];
    const float* fi    = (const float*)d_in[4];
    const float* wu    = (const float*)d_in[5];
    const float* wi    = (const float*)d_in[6];
    const int* row = edge;
    const int* col = edge + E;

    const int NB  = (N + 255) / 256;
    const int EB  = (E + 255) / 256;
    const int XB8 = ((N * 8) + 255) / 256;

    // Workspace carve (aligned 256B). ~88 MB total.
    char* p = (char*)d_ws;
    auto carve = [&](size_t bytes) -> void* {
        void* q = (void*)p;
        p += (bytes + 255) & ~(size_t)255;
        return q;
    };
    float* dinv    = (float*)carve((size_t)N * 4);
    int*   deg     = (int*)  carve((size_t)N * 4);
    int*   rs      = (int*)  carve((size_t)(N + 1) * 4);
    int*   cursor  = (int*)  carve((size_t)N * 4);
    int*   bsum    = (int*)  carve(1024 * 4);
    int2*  csr     = (int2*) carve((size_t)E * 8);      // packed (src, norm)
    unsigned short* wub = (unsigned short*)carve((size_t)EMB_D * FEAT_K * 2);
    unsigned short* wib = (unsigned short*)carve((size_t)EMB_D * FEAT_K * 2);
    uint4* x0 = (uint4*)carve((size_t)N * EMB_D * 2);   // bf16 layer states
    uint4* x1 = (uint4*)carve((size_t)N * EMB_D * 2);
    uint4* x2 = (uint4*)carve((size_t)N * EMB_D * 2);
    uint4* x3 = (uint4*)carve((size_t)N * EMB_D * 2);

    float* outp = (float*)d_out;   // [N][64] == [u_final; i_final]

    hipMemsetAsync(deg, 0, (size_t)N * 4, stream);
    k_count<<<EB, 256, 0, stream>>>(col, deg, E);
    k_dinv<<<NB, 256, 0, stream>>>(deg, dinv, N);
    k_scan_a<<<NB, 256, 0, stream>>>(deg, rs, bsum, N);
    k_scan_b<<<1, 1024, 0, stream>>>(bsum, NB);
    k_scan_c<<<NB, 256, 0, stream>>>(rs, bsum, cursor, N, E);
    k_fill<<<EB, 256, 0, stream>>>(row, col, dinv, cursor, csr, E);
    k_cvtw<<<(2 * EMB_D * FEAT_K) / 256, 256, 0, stream>>>(wu, wi, wub, wib);
    k_init<<<XB8, 256, 0, stream>>>((const float4*)emb_u, (const float4*)emb_i,
                                    x0, U * 8, N * 8);
    // layers 1..3: pure propagation, bf16 state
    k_agg<<<XB8, 256, 0, stream>>>(x0, x1, rs, csr, N);
    k_agg<<<XB8, 256, 0, stream>>>(x1, x2, rs, csr, N);
    k_agg<<<XB8, 256, 0, stream>>>(x2, x3, rs, csr, N);
    // layer 4 fused with the (x0..x4) sum and 1/25 scale -> d_out
    k_agg4<<<XB8, 256, 0, stream>>>(x3, x1, x2, emb_u, emb_i, outp, rs, csr, N, U);
    // projection: out += F @ W^T (user + item in one launch)
    const int nbU = (U + 63) / 64;               // 1563
    const int nbI = (N - U + 63) / 64;           // 782
    k_projm<<<nbU + nbI, 256, 0, stream>>>(fu, fi, wub, wib, outp, nbU, U, N - U);
}

// Round 14
// 280.832 us; speedup vs baseline: 1.1286x; 1.0001x over previous
//
#include <hip/hip_runtime.h>

// Problem constants (match reference)
#define U_NODES 100000
#define I_NODES 50000
#define N_NODES 150000   // U + I
#define EMB_D   64
#define FEAT_K  256
#define N_LAYERS 4

typedef __attribute__((ext_vector_type(8))) short short8;
typedef __attribute__((ext_vector_type(4))) float f32x4;

// f32 -> bf16 round-to-nearest-even (bit trick)
static __device__ __forceinline__ unsigned short f2bf(float f) {
    unsigned u = __builtin_bit_cast(unsigned, f);
    u += 0x7fffu + ((u >> 16) & 1u);
    return (unsigned short)(u >> 16);
}
static __device__ __forceinline__ float bflo(unsigned u) {
    return __builtin_bit_cast(float, u << 16);
}
static __device__ __forceinline__ float bfhi(unsigned u) {
    return __builtin_bit_cast(float, u & 0xffff0000u);
}

// ---------------------------------------------------------------------------
__global__ __launch_bounds__(256) void k_count(const int* __restrict__ col,
                                               int* __restrict__ deg, int E) {
    int e = blockIdx.x * 256 + threadIdx.x;
    if (e < E) atomicAdd(&deg[col[e]], 1);
}

__global__ __launch_bounds__(256) void k_dinv(const int* __restrict__ deg,
                                              float* __restrict__ dinv, int n) {
    int i = blockIdx.x * 256 + threadIdx.x;
    if (i < n) {
        int d = deg[i];
        dinv[i] = (d > 0) ? rsqrtf((float)d) : 0.0f;
    }
}

__global__ __launch_bounds__(256) void k_scan_a(const int* __restrict__ deg,
                                                int* __restrict__ rs,
                                                int* __restrict__ bsum, int n) {
    __shared__ int wsum[4];
    int t = threadIdx.x;
    int i = blockIdx.x * 256 + t;
    int v = (i < n) ? deg[i] : 0;
    int x = v;
    #pragma unroll
    for (int off = 1; off < 64; off <<= 1) {
        int y = __shfl_up(x, off, 64);
        if ((t & 63) >= off) x += y;
    }
    if ((t & 63) == 63) wsum[t >> 6] = x;
    __syncthreads();
    int base = 0;
    #pragma unroll
    for (int w = 0; w < 4; ++w) base += (w < (t >> 6)) ? wsum[w] : 0;
    if (i < n) rs[i] = base + x - v;
    if (t == 255) bsum[blockIdx.x] = base + x;
}

__global__ __launch_bounds__(1024) void k_scan_b(int* __restrict__ bs, int nb) {
    __shared__ int wsum[16];
    int t = threadIdx.x;
    int v = (t < nb) ? bs[t] : 0;
    int x = v;
    #pragma unroll
    for (int off = 1; off < 64; off <<= 1) {
        int y = __shfl_up(x, off, 64);
        if ((t & 63) >= off) x += y;
    }
    if ((t & 63) == 63) wsum[t >> 6] = x;
    __syncthreads();
    int base = 0;
    #pragma unroll
    for (int w = 0; w < 16; ++w) base += (w < (t >> 6)) ? wsum[w] : 0;
    if (t < nb) bs[t] = base + x - v;
}

__global__ __launch_bounds__(256) void k_scan_c(int* __restrict__ rs,
                                                const int* __restrict__ bsum,
                                                int* __restrict__ cursor,
                                                int n, int E) {
    int i = blockIdx.x * 256 + threadIdx.x;
    if (i < n) {
        int v = rs[i] + bsum[blockIdx.x];
        rs[i] = v;
        cursor[i] = v;
    }
    if (i == 0) rs[n] = E;
}

// CSR fill: ONE scattered 8B PLAIN store per edge (src, norm packed).
// R13 lesson: the nt-store was the write-amplifier — it streamed every 8B
// store to HBM at 64B line granularity (1M x 64B ~= the 67 MB measured).
// The 8 MB csr region fits aggregate L2 (32 MB); a cached store is written
// back ~once per line.
__global__ __launch_bounds__(256) void k_fill(const int* __restrict__ row,
                                              const int* __restrict__ col,
                                              const float* __restrict__ dinv,
                                              int* __restrict__ cursor,
                                              int2* __restrict__ csr, int E) {
    int e = blockIdx.x * 256 + threadIdx.x;
    if (e < E) {
        int r = row[e], c = col[e];
        int p = atomicAdd(&cursor[c], 1);
        int2 v;
        v.x = r;
        v.y = __builtin_bit_cast(int, dinv[r] * dinv[c]);
        csr[p] = v;
    }
}

// Convert W matrices to bf16 (once per call; 32K elements total)
__global__ __launch_bounds__(256) void k_cvtw(const float* __restrict__ wu,
                                              const float* __restrict__ wi,
                                              unsigned short* __restrict__ wub,
                                              unsigned short* __restrict__ wib) {
    int i = blockIdx.x * 256 + threadIdx.x;
    if (i < EMB_D * FEAT_K) wub[i] = f2bf(wu[i]);
    else                    wib[i - EMB_D * FEAT_K] = f2bf(wi[i - EMB_D * FEAT_K]);
}

// Init: x0 (bf16) = concat(emb_users, emb_items). One thread per 8 elements.
__global__ __launch_bounds__(256) void k_init(const float4* __restrict__ eu,
                                              const float4* __restrict__ ei,
                                              uint4* __restrict__ x,
                                              int n8u, int n8) {
    int i = blockIdx.x * 256 + threadIdx.x;
    if (i >= n8) return;
    const float4* s = (i < n8u) ? (eu + (size_t)i * 2) : (ei + (size_t)(i - n8u) * 2);
    float4 p0 = s[0], p1 = s[1];
    uint4 r;
    r.x = (unsigned)f2bf(p0.x) | ((unsigned)f2bf(p0.y) << 16);
    r.y = (unsigned)f2bf(p0.z) | ((unsigned)f2bf(p0.w) << 16);
    r.z = (unsigned)f2bf(p1.x) | ((unsigned)f2bf(p1.y) << 16);
    r.w = (unsigned)f2bf(p1.z) | ((unsigned)f2bf(p1.w) << 16);
    x[i] = r;
}

// NOTE: macro params use trailing-underscore names (R5 lesson: never collide
// with .x/.y/.z/.w member tokens).
#define ACC8(v_, w_)                       \
    s0 = fmaf(bflo((v_).x), (w_), s0);     \
    s1 = fmaf(bfhi((v_).x), (w_), s1);     \
    s2 = fmaf(bflo((v_).y), (w_), s2);     \
    s3 = fmaf(bfhi((v_).y), (w_), s3);     \
    s4 = fmaf(bflo((v_).z), (w_), s4);     \
    s5 = fmaf(bfhi((v_).z), (w_), s5);     \
    s6 = fmaf(bflo((v_).w), (w_), s6);     \
    s7 = fmaf(bfhi((v_).w), (w_), s7);

// Masked 4-wide gather round: always 4 outstanding gathers; OOB lanes are
// clamped to the last edge with weight zeroed.
#define GATHER4(xsrc_, ep_, em_)                                              \
    {                                                                         \
        int i0_ = (ep_), i1_ = min((ep_) + 1, (em_));                         \
        int i2_ = min((ep_) + 2, (em_)), i3_ = min((ep_) + 3, (em_));         \
        int2 pa_ = csr[i0_], pb_ = csr[i1_], pc_ = csr[i2_], pd_ = csr[i3_];  \
        float wa_ = __builtin_bit_cast(float, pa_.y);                         \
        float wb_ = ((ep_) + 1 <= (em_)) ? __builtin_bit_cast(float, pb_.y) : 0.f; \
        float wc_ = ((ep_) + 2 <= (em_)) ? __builtin_bit_cast(float, pc_.y) : 0.f; \
        float wd_ = ((ep_) + 3 <= (em_)) ? __builtin_bit_cast(float, pd_.y) : 0.f; \
        uint4 va_ = (xsrc_)[(size_t)pa_.x * 8 + lane];                        \
        uint4 vb_ = (xsrc_)[(size_t)pb_.x * 8 + lane];                        \
        uint4 vc_ = (xsrc_)[(size_t)pc_.x * 8 + lane];                        \
        uint4 vd_ = (xsrc_)[(size_t)pd_.x * 8 + lane];                        \
        ACC8(va_, wa_) ACC8(vb_, wb_) ACC8(vc_, wc_) ACC8(vd_, wd_)           \
    }

// Pull-mode aggregation (layers 1..3), bf16 state: 8 lanes/node, 16B/lane.
__global__ __launch_bounds__(256) void k_agg(const uint4* __restrict__ xin,
                                             uint4* __restrict__ xout,
                                             const int* __restrict__ rs,
                                             const int2* __restrict__ csr,
                                             int n_nodes) {
    int idx = blockIdx.x * 256 + threadIdx.x;
    int node = idx >> 3;
    int lane = idx & 7;
    if (node >= n_nodes) return;
    int e0 = rs[node], e1 = rs[node + 1];
    float s0 = 0.f, s1 = 0.f, s2 = 0.f, s3 = 0.f;
    float s4 = 0.f, s5 = 0.f, s6 = 0.f, s7 = 0.f;
    int em = e1 - 1;
    for (int ep = e0; ep < e1; ep += 4) GATHER4(xin, ep, em)
    uint4 r;
    r.x = (unsigned)f2bf(s0) | ((unsigned)f2bf(s1) << 16);
    r.y = (unsigned)f2bf(s2) | ((unsigned)f2bf(s3) << 16);
    r.z = (unsigned)f2bf(s4) | ((unsigned)f2bf(s5) << 16);
    r.w = (unsigned)f2bf(s6) | ((unsigned)f2bf(s7) << 16);
    xout[(size_t)node * 8 + lane] = r;
}

// Layer 4 + fused sum: s = gather(x3); out_row = (emb + x1 + x2 + x3 + s)/25
__global__ __launch_bounds__(256) void k_agg4(const uint4* __restrict__ x3,
                                              const uint4* __restrict__ x1,
                                              const uint4* __restrict__ x2,
                                              const float* __restrict__ embU,
                                              const float* __restrict__ embI,
                                              float* __restrict__ outp,
                                              const int* __restrict__ rs,
                                              const int2* __restrict__ csr,
                                              int n_nodes, int U) {
    int idx = blockIdx.x * 256 + threadIdx.x;
    int node = idx >> 3;
    int lane = idx & 7;
    if (node >= n_nodes) return;
    int e0 = rs[node], e1 = rs[node + 1];
    float s0 = 0.f, s1 = 0.f, s2 = 0.f, s3 = 0.f;
    float s4 = 0.f, s5 = 0.f, s6 = 0.f, s7 = 0.f;
    int em = e1 - 1;
    for (int ep = e0; ep < e1; ep += 4) GATHER4(x3, ep, em)
    uint4 v1 = x1[(size_t)node * 8 + lane];
    uint4 v2 = x2[(size_t)node * 8 + lane];
    uint4 v3 = x3[(size_t)node * 8 + lane];
    const float* ebp = (node < U) ? (embU + (size_t)node * EMB_D)
                                  : (embI + (size_t)(node - U) * EMB_D);
    float4 ea = ((const float4*)ebp)[lane * 2];
    float4 eb2 = ((const float4*)ebp)[lane * 2 + 1];
    const float sc = 1.0f / 25.0f;
    float4 o0, o1;
    o0.x = (ea.x  + bflo(v1.x) + bflo(v2.x) + bflo(v3.x) + s0) * sc;
    o0.y = (ea.y  + bfhi(v1.x) + bfhi(v2.x) + bfhi(v3.x) + s1) * sc;
    o0.z = (ea.z  + bflo(v1.y) + bflo(v2.y) + bflo(v3.y) + s2) * sc;
    o0.w = (ea.w  + bfhi(v1.y) + bfhi(v2.y) + bfhi(v3.y) + s3) * sc;
    o1.x = (eb2.x + bflo(v1.z) + bflo(v2.z) + bflo(v3.z) + s4) * sc;
    o1.y = (eb2.y + bfhi(v1.z) + bfhi(v2.z) + bfhi(v3.z) + s5) * sc;
    o1.z = (eb2.z + bflo(v1.w) + bflo(v2.w) + bflo(v3.w) + s6) * sc;
    o1.w = (eb2.w + bfhi(v1.w) + bfhi(v2.w) + bfhi(v3.w) + s7) * sc;
    float4* op = (float4*)(outp + (size_t)node * EMB_D) + lane * 2;
    op[0] = o0;
    op[1] = o1;
}

// ---------------------------------------------------------------------------
// Projection via MFMA bf16: out[r][c] += (F @ W^T)[r][c]   (sum/25 already in out)
// REBUILT (R13): one block = ONE 16-row tile. 4 waves; wave w owns n-tile w
// (16 cols) with its B-slice in 32 VGPRs (8 x uint4, loaded once from the
// 32 KB bf16 W — L2-hot). A (16 rows x 256 f32 = 16 KB) is staged ASYNC into
// LDS via global_load_lds width=16 (linear dest per HW rule; SOURCE
// pre-swizzled x ^= (row&7)<<4; reads apply the same XOR -> bank-minimal).
// 16 KB LDS -> 8 blocks/CU = 32 waves/CU; 9375 blocks, ~128 KB/CU of F in
// flight >> BW-latency product.
// Fragment layouts (16x16x32 bf16, m89/m91-verified):
//   A: row = l&15, k = (l>>4)*8 + j ;  B: col = l&15, k = (l>>4)*8 + j
//   D: col = l&15, row = (l>>4)*4 + reg
__global__ __launch_bounds__(256) void k_projm(const float* __restrict__ FU,
                                               const float* __restrict__ FI,
                                               const unsigned short* __restrict__ WUb,
                                               const unsigned short* __restrict__ WIb,
                                               float* __restrict__ out,
                                               int nbU, int U, int I) {
    __shared__ float sA[16 * 256];   // 16 KB: 16 rows x 256 f32, col-swizzled
    const bool isU = ((int)blockIdx.x < nbU);
    const float* __restrict__ F = isU ? FU : FI;
    const uint4* __restrict__ Wb4 = (const uint4*)(isU ? WUb : WIb);
    float* __restrict__ o = isU ? out : out + (size_t)U * EMB_D;
    const int M = isU ? U : I;
    const int tile = isU ? (int)blockIdx.x : (int)blockIdx.x - nbU;
    const int row0 = tile * 16;
    const int wave = threadIdx.x >> 6;    // 0..3 = n-tile
    const int lane = threadIdx.x & 63;
    const int l15  = lane & 15;
    const int kq   = lane >> 4;

    // B-slice into registers: col = wave*16 + l15, 8 k-steps
    const uint4* wp = Wb4 + (size_t)(wave * 16 + l15) * 32 + kq;
    uint4 B0 = wp[0],  B1 = wp[4],  B2 = wp[8],  B3 = wp[12];
    uint4 B4 = wp[16], B5 = wp[20], B6 = wp[24], B7 = wp[28];

    // Stage A tile: instruction j covers LDS row r = wave*4 + j (1 KB each).
    // HW writes lane l at (lds_base + l*16); source is per-lane, pre-swizzled.
    #pragma unroll
    for (int j = 0; j < 4; ++j) {
        int r = wave * 4 + j;
        int grow = min(row0 + r, M - 1);           // clamp: dup row, discarded
        int sboff = (lane * 16) ^ ((r & 7) << 4);  // swizzled byte col in row
        const float* src = F + (size_t)grow * FEAT_K + (sboff >> 2);
        __builtin_amdgcn_global_load_lds(
            (const __attribute__((address_space(1))) void*)src,
            (__attribute__((address_space(3))) void*)(sA + r * 256),
            16, 0, 0);
    }
    __syncthreads();

    f32x4 acc = {0.f, 0.f, 0.f, 0.f};
    const char* arow_p = (const char*)(sA + l15 * 256);
    const int sw = (l15 & 7) << 4;

#define CVT2(d_, lo_, hi_) asm("v_cvt_pk_bf16_f32 %0, %1, %2" : "=v"(d_) : "v"(lo_), "v"(hi_))
#define KS(ks_, B_)                                                            \
    {                                                                          \
        int cb = (ks_) * 128 + kq * 32;                                        \
        f32x4 lo = *(const f32x4*)(arow_p + ((cb) ^ sw));                      \
        f32x4 hi = *(const f32x4*)(arow_p + ((cb + 16) ^ sw));                 \
        unsigned p0, p1, p2, p3;                                               \
        CVT2(p0, lo[0], lo[1]); CVT2(p1, lo[2], lo[3]);                        \
        CVT2(p2, hi[0], hi[1]); CVT2(p3, hi[2], hi[3]);                        \
        uint4 up; up.x = p0; up.y = p1; up.z = p2; up.w = p3;                  \
        short8 av = __builtin_bit_cast(short8, up);                            \
        short8 bv = __builtin_bit_cast(short8, B_);                            \
        acc = __builtin_amdgcn_mfma_f32_16x16x32_bf16(av, bv, acc, 0, 0, 0);   \
    }

    KS(0, B0) KS(1, B1) KS(2, B2) KS(3, B3)
    KS(4, B4) KS(5, B5) KS(6, B6) KS(7, B7)
#undef KS
#undef CVT2

    // Epilogue: D col = wave*16 + l15, row = row0 + kq*4 + r
    #pragma unroll
    for (int r = 0; r < 4; ++r) {
        int grow = row0 + kq * 4 + r;
        if (grow < M) {
            float* op = o + (size_t)grow * EMB_D + wave * 16 + l15;
            op[0] += acc[r];
        }
    }
}

// ---------------------------------------------------------------------------
extern "C" void kernel_launch(void* const* d_in, const int* in_sizes, int n_in,
                              void* d_out, int out_size, void* d_ws, size_t ws_size,
                              hipStream_t stream) {
    const int E = in_sizes[0] / 2;
    const int N = N_NODES, U = U_NODES;

    const int*   edge  = (const int*)d_in[0];
    const float* emb_u = (const float*)d_in[1];
    const float* emb_i = (const float*)d_in[2];
    const float* fu    = (const float*)d_in[3];
    const float* fi    = (const float*)d_in[4];
    const float* wu    = (const float*)d_in[5];
    const float* wi    = (const float*)d_in[6];
    const int* row = edge;
    const int* col = edge + E;

    const int NB  = (N + 255) / 256;
    const int EB  = (E + 255) / 256;
    const int XB8 = ((N * 8) + 255) / 256;

    // Workspace carve (aligned 256B). ~88 MB total.
    char* p = (char*)d_ws;
    auto carve = [&](size_t bytes) -> void* {
        void* q = (void*)p;
        p += (bytes + 255) & ~(size_t)255;
        return q;
    };
    float* dinv    = (float*)carve((size_t)N * 4);
    int*   deg     = (int*)  carve((size_t)N * 4);
    int*   rs      = (int*)  carve((size_t)(N + 1) * 4);
    int*   cursor  = (int*)  carve((size_t)N * 4);
    int*   bsum    = (int*)  carve(1024 * 4);
    int2*  csr     = (int2*) carve((size_t)E * 8);      // packed (src, norm)
    unsigned short* wub = (unsigned short*)carve((size_t)EMB_D * FEAT_K * 2);
    unsigned short* wib = (unsigned short*)carve((size_t)EMB_D * FEAT_K * 2);
    uint4* x0 = (uint4*)carve((size_t)N * EMB_D * 2);   // bf16 layer states
    uint4* x1 = (uint4*)carve((size_t)N * EMB_D * 2);
    uint4* x2 = (uint4*)carve((size_t)N * EMB_D * 2);
    uint4* x3 = (uint4*)carve((size_t)N * EMB_D * 2);

    float* outp = (float*)d_out;   // [N][64] == [u_final; i_final]

    hipMemsetAsync(deg, 0, (size_t)N * 4, stream);
    k_count<<<EB, 256, 0, stream>>>(col, deg, E);
    k_dinv<<<NB, 256, 0, stream>>>(deg, dinv, N);
    k_scan_a<<<NB, 256, 0, stream>>>(deg, rs, bsum, N);
    k_scan_b<<<1, 1024, 0, stream>>>(bsum, NB);
    k_scan_c<<<NB, 256, 0, stream>>>(rs, bsum, cursor, N, E);
    k_fill<<<EB, 256, 0, stream>>>(row, col, dinv, cursor, csr, E);
    k_cvtw<<<(2 * EMB_D * FEAT_K) / 256, 256, 0, stream>>>(wu, wi, wub, wib);
    k_init<<<XB8, 256, 0, stream>>>((const float4*)emb_u, (const float4*)emb_i,
                                    x0, U * 8, N * 8);
    // layers 1..3: pure propagation, bf16 state
    k_agg<<<XB8, 256, 0, stream>>>(x0, x1, rs, csr, N);
    k_agg<<<XB8, 256, 0, stream>>>(x1, x2, rs, csr, N);
    k_agg<<<XB8, 256, 0, stream>>>(x2, x3, rs, csr, N);
    // layer 4 fused with the (x0..x4) sum and 1/25 scale -> d_out
    k_agg4<<<XB8, 256, 0, stream>>>(x3, x1, x2, emb_u, emb_i, outp, rs, csr, N, U);
    // projection: out += F @ W^T (user + item in one launch; 16-row tiles)
    const int nbU = (U + 15) / 16;               // 6250
    const int nbI = (N - U + 15) / 16;           // 3125
    k_projm<<<nbU + nbI, 256, 0, stream>>>(fu, fi, wub, wib, outp, nbU, U, N - U);
}